// Round 5
// baseline (442.241 us; speedup 1.0000x reference)
//
#include <hip/hip_runtime.h>

// Grid2Mesh via linearity: edge_pre = gm.W1a + P1[src] + P2[dst],
// P1 = rect.W1b (fused into rect-MLP kernel), P2 = mesh.W1c.
// bf16 MFMA 16x16x32 swapped operands -> lane owns an output row.
// W staged in LDS wave-fragment-contiguous (zero bank conflict).
// R5: 4 tiles/wave grid-stride loops (amortize W staging), shallow pipeline
// (pair @t+2, P gathers @t+1 issued under MFMA), NT stores for out0.

typedef __bf16 bf16x8 __attribute__((ext_vector_type(8)));
typedef __bf16 bf16x4 __attribute__((ext_vector_type(4)));
typedef float f32x4 __attribute__((ext_vector_type(4)));

#define E_CNT 262144
#define NG_CNT 65536
#define NM_CNT 8192

__device__ __forceinline__ float fast_tanh(float x) {
  float e = __expf(2.f * x);
  return 1.f - 2.f / (1.f + e);
}

// Stage W (KDIMx128 f32 row-major) into LDS wave-fragment bf16:
// chunk c=(kk*8+n)*64+lane, lane=(q*16+cx): holds W[kk*32+q*8+j][n*16+cx].
template <int KDIM>
__device__ __forceinline__ void stage_W(const float* __restrict__ W, __bf16* wt) {
  constexpr int NCH = (KDIM / 32) * 8 * 64;
  for (int c = threadIdx.x; c < NCH; c += blockDim.x) {
    const int lane6 = c & 63, cx = lane6 & 15, qq = lane6 >> 4;
    const int kkn = c >> 6, kk = kkn >> 3, nn = kkn & 7;
    const int k0 = kk * 32 + qq * 8, col = nn * 16 + cx;
    bf16x8 v;
#pragma unroll
    for (int j = 0; j < 8; ++j) v[j] = (__bf16)W[(k0 + j) * 128 + col];
    *(bf16x8*)(wt + c * 8) = v;
  }
}

// tanh + LN + residual epilogue; acc[n][j] = pre[row][n*16+q*4+j].
template <bool STORE_D, bool NT>
__device__ __forceinline__ void mlp_epilogue(f32x4* acc, const f32x4* R,
                                             const float* gvec,
                                             const float* bvec, int q,
                                             float* op, __bf16* dp) {
  float s1 = 0.f, s2 = 0.f;
#pragma unroll
  for (int n = 0; n < 8; ++n)
#pragma unroll
    for (int j = 0; j < 4; ++j) {
      float v = fast_tanh(acc[n][j]);
      acc[n][j] = v;
      s1 += v;
      s2 += v * v;
    }
  s1 += __shfl_xor(s1, 16, 64);
  s2 += __shfl_xor(s2, 16, 64);
  s1 += __shfl_xor(s1, 32, 64);
  s2 += __shfl_xor(s2, 32, 64);
  const float mu = s1 * (1.f / 128.f);
  const float rs = rsqrtf(s2 * (1.f / 128.f) - mu * mu + 1e-5f);
#pragma unroll
  for (int n = 0; n < 8; ++n) {
    const f32x4 G = *(const f32x4*)(gvec + n * 16 + q * 4);
    const f32x4 Bv = *(const f32x4*)(bvec + n * 16 + q * 4);
    f32x4 o;
    bf16x4 db;
#pragma unroll
    for (int j = 0; j < 4; ++j) {
      const float d = (acc[n][j] - mu) * rs * G[j] + Bv[j];
      o[j] = R[n][j] + d;
      db[j] = (__bf16)d;
    }
    if (NT)
      __builtin_nontemporal_store(o, (f32x4*)(op + n * 16 + q * 4));
    else
      *(f32x4*)(op + n * 16 + q * 4) = o;
    if (STORE_D) *(bf16x4*)(dp + n * 16 + q * 4) = db;
  }
}

// Edge kernel: out0 = gm + LN(tanh(gm.W1a + P1[src] + P2[dst]))*g+b.
// Grid-stride loop, shallow pipeline: pair @t+2, P gathers @t+1.
template <bool STORE_D>
__global__ __launch_bounds__(256) __attribute__((amdgpu_waves_per_eu(3, 4)))
void edge_kernel(const float* __restrict__ gm, const int* __restrict__ pair,
                 const __bf16* __restrict__ P1, const __bf16* __restrict__ P2,
                 const float* __restrict__ W, const float* __restrict__ gvec,
                 const float* __restrict__ bvec, float* __restrict__ out,
                 __bf16* __restrict__ delta_out, int M) {
  __shared__ __bf16 wt[2048 * 8];  // 32 KB
  stage_W<128>(W, wt);
  __syncthreads();
  const int tid = threadIdx.x, lane = tid & 63, wid = tid >> 6;
  const int r = lane & 15, q = lane >> 4;
  const __bf16* wl = wt + lane * 8;
  const int nw = gridDim.x * 4;  // total waves
  const int tiles = M >> 4;
  int t = blockIdx.x * 4 + wid;
  if (t >= tiles) return;

  // prologue: P gathers for tile t in flight, pair for t+nw loaded
  int2 sd = *(const int2*)(pair + 2 * (size_t)((t << 4) + r));
  bf16x4 pg1[8], pg2[8];
  {
    const __bf16* p1 = P1 + (size_t)sd.x * 128 + q * 4;
    const __bf16* p2 = P2 + (size_t)sd.y * 128 + q * 4;
#pragma unroll
    for (int n = 0; n < 8; ++n) {
      pg1[n] = *(const bf16x4*)(p1 + n * 16);
      pg2[n] = *(const bf16x4*)(p2 + n * 16);
    }
  }
  int2 sd_next = {0, 0};
  if (t + nw < tiles)
    sd_next = *(const int2*)(pair + 2 * (size_t)(((t + nw) << 4) + r));

  for (; t < tiles; t += nw) {
    const int row = (t << 4) + r;
    const float* pa = gm + (size_t)row * 128;
    // contiguous loads for this tile (A fragments + residual row)
    f32x4 F[4][2];
#pragma unroll
    for (int kk = 0; kk < 4; ++kk) {
      F[kk][0] = *(const f32x4*)(pa + kk * 32 + q * 8);
      F[kk][1] = *(const f32x4*)(pa + kk * 32 + q * 8 + 4);
    }
    f32x4 R[8];
#pragma unroll
    for (int n = 0; n < 8; ++n) R[n] = *(const f32x4*)(pa + n * 16 + q * 4);
    // acc init from P gathers (issued prologue / previous iteration)
    f32x4 acc[8];
#pragma unroll
    for (int n = 0; n < 8; ++n)
#pragma unroll
      for (int j = 0; j < 4; ++j)
        acc[n][j] = (float)pg1[n][j] + (float)pg2[n][j];
    // issue NEXT tile's gathers now -> latency hidden under MFMA + epilogue
    if (t + nw < tiles) {
      const __bf16* p1 = P1 + (size_t)sd_next.x * 128 + q * 4;
      const __bf16* p2 = P2 + (size_t)sd_next.y * 128 + q * 4;
#pragma unroll
      for (int n = 0; n < 8; ++n) {
        pg1[n] = *(const bf16x4*)(p1 + n * 16);
        pg2[n] = *(const bf16x4*)(p2 + n * 16);
      }
      if (t + 2 * nw < tiles)
        sd_next = *(const int2*)(pair + 2 * (size_t)(((t + 2 * nw) << 4) + r));
    }
    bf16x8 ab[4];
#pragma unroll
    for (int kk = 0; kk < 4; ++kk)
#pragma unroll
      for (int j = 0; j < 4; ++j) {
        ab[kk][j] = (__bf16)F[kk][0][j];
        ab[kk][4 + j] = (__bf16)F[kk][1][j];
      }
#pragma unroll
    for (int kk = 0; kk < 4; ++kk)
#pragma unroll
      for (int n = 0; n < 8; ++n)
        acc[n] = __builtin_amdgcn_mfma_f32_16x16x32_bf16(
            *(const bf16x8*)(wl + (kk * 8 + n) * 512), ab[kk], acc[n], 0, 0, 0);
    mlp_epilogue<STORE_D, true>(
        acc, R, gvec, bvec, q, out + (size_t)row * 128,
        STORE_D ? delta_out + (size_t)row * 128 : nullptr);
  }
}

// Fused rect kernel: P1 = bf16(rect.W1b) AND out1 = rect + mlp(rect, W3).
__global__ __launch_bounds__(256) __attribute__((amdgpu_waves_per_eu(2, 4)))
void rect_fused_kernel(const float* __restrict__ rect,
                       const float* __restrict__ W1b,
                       const float* __restrict__ W3,
                       const float* __restrict__ gvec,
                       const float* __restrict__ bvec,
                       float* __restrict__ out1, __bf16* __restrict__ P1,
                       int M) {
  __shared__ __bf16 wt[4096 * 8];  // 64 KB: [0]=W1b frags, [16384]=W3 frags
  stage_W<128>(W1b, wt);
  stage_W<128>(W3, wt + 16384);
  __syncthreads();
  const int tid = threadIdx.x, lane = tid & 63, wid = tid >> 6;
  const int r = lane & 15, q = lane >> 4;
  const __bf16* wl = wt + lane * 8;
  const int nw = gridDim.x * 4;
  const int tiles = M >> 4;
  for (int t = blockIdx.x * 4 + wid; t < tiles; t += nw) {
    const int row = (t << 4) + r;
    const float* pa = rect + (size_t)row * 128;
    f32x4 F[4][2];
#pragma unroll
    for (int kk = 0; kk < 4; ++kk) {
      F[kk][0] = *(const f32x4*)(pa + kk * 32 + q * 8);
      F[kk][1] = *(const f32x4*)(pa + kk * 32 + q * 8 + 4);
    }
    f32x4 R[8];
#pragma unroll
    for (int n = 0; n < 8; ++n) R[n] = *(const f32x4*)(pa + n * 16 + q * 4);
    bf16x8 ab[4];
#pragma unroll
    for (int kk = 0; kk < 4; ++kk)
#pragma unroll
      for (int j = 0; j < 4; ++j) {
        ab[kk][j] = (__bf16)F[kk][0][j];
        ab[kk][4 + j] = (__bf16)F[kk][1][j];
      }
    f32x4 acc[8] = {};
#pragma unroll
    for (int kk = 0; kk < 4; ++kk)
#pragma unroll
      for (int n = 0; n < 8; ++n)
        acc[n] = __builtin_amdgcn_mfma_f32_16x16x32_bf16(
            *(const bf16x8*)(wl + (kk * 8 + n) * 512), ab[kk], acc[n], 0, 0, 0);
    __bf16* pp = P1 + (size_t)row * 128;
#pragma unroll
    for (int n = 0; n < 8; ++n) {
      bf16x4 o;
#pragma unroll
      for (int j = 0; j < 4; ++j) o[j] = (__bf16)acc[n][j];
      *(bf16x4*)(pp + n * 16 + q * 4) = o;
    }
    f32x4 acc2[8] = {};
#pragma unroll
    for (int kk = 0; kk < 4; ++kk)
#pragma unroll
      for (int n = 0; n < 8; ++n)
        acc2[n] = __builtin_amdgcn_mfma_f32_16x16x32_bf16(
            *(const bf16x8*)(wl + 16384 + (kk * 8 + n) * 512), ab[kk], acc2[n],
            0, 0, 0);
    mlp_epilogue<false, false>(acc2, R, gvec, bvec, q,
                               out1 + (size_t)row * 128, nullptr);
  }
}

// Plain K=128 MLP (fallback rect path): out = A + mlp(A, W).
__global__ __launch_bounds__(256) __attribute__((amdgpu_waves_per_eu(3, 4)))
void mlp128_kernel(const float* __restrict__ A, const float* __restrict__ W,
                   const float* __restrict__ gvec, const float* __restrict__ bvec,
                   float* __restrict__ out, int M) {
  __shared__ __bf16 wt[2048 * 8];
  stage_W<128>(W, wt);
  __syncthreads();
  const int tid = threadIdx.x, lane = tid & 63, wid = tid >> 6;
  const int r = lane & 15, q = lane >> 4;
  const __bf16* wl = wt + lane * 8;
  const int nw = gridDim.x * 4;
  const int tiles = M >> 4;
  for (int t = blockIdx.x * 4 + wid; t < tiles; t += nw) {
    const int row = (t << 4) + r;
    const float* pa = A + (size_t)row * 128;
    f32x4 F[4][2];
#pragma unroll
    for (int kk = 0; kk < 4; ++kk) {
      F[kk][0] = *(const f32x4*)(pa + kk * 32 + q * 8);
      F[kk][1] = *(const f32x4*)(pa + kk * 32 + q * 8 + 4);
    }
    f32x4 R[8];
#pragma unroll
    for (int n = 0; n < 8; ++n) R[n] = *(const f32x4*)(pa + n * 16 + q * 4);
    bf16x8 ab[4];
#pragma unroll
    for (int kk = 0; kk < 4; ++kk)
#pragma unroll
      for (int j = 0; j < 4; ++j) {
        ab[kk][j] = (__bf16)F[kk][0][j];
        ab[kk][4 + j] = (__bf16)F[kk][1][j];
      }
    f32x4 acc[8] = {};
#pragma unroll
    for (int kk = 0; kk < 4; ++kk)
#pragma unroll
      for (int n = 0; n < 8; ++n)
        acc[n] = __builtin_amdgcn_mfma_f32_16x16x32_bf16(
            *(const bf16x8*)(wl + (kk * 8 + n) * 512), ab[kk], acc[n], 0, 0, 0);
    mlp_epilogue<false, false>(acc, R, gvec, bvec, q, out + (size_t)row * 128,
                               nullptr);
  }
}

// Dense K=128 linear, bf16 out (P1 fallback / P2).
__global__ __launch_bounds__(256) __attribute__((amdgpu_waves_per_eu(3, 4)))
void lin_kernel(const float* __restrict__ A, const float* __restrict__ W,
                __bf16* __restrict__ out, int M) {
  __shared__ __bf16 wt[2048 * 8];
  stage_W<128>(W, wt);
  __syncthreads();
  const int tid = threadIdx.x, lane = tid & 63, wid = tid >> 6;
  const int r = lane & 15, q = lane >> 4;
  const __bf16* wl = wt + lane * 8;
  const int nw = gridDim.x * 4;
  const int tiles = M >> 4;
  for (int t = blockIdx.x * 4 + wid; t < tiles; t += nw) {
    const int row = (t << 4) + r;
    const float* pa = A + (size_t)row * 128;
    f32x4 F[4][2];
#pragma unroll
    for (int kk = 0; kk < 4; ++kk) {
      F[kk][0] = *(const f32x4*)(pa + kk * 32 + q * 8);
      F[kk][1] = *(const f32x4*)(pa + kk * 32 + q * 8 + 4);
    }
    bf16x8 ab[4];
#pragma unroll
    for (int kk = 0; kk < 4; ++kk)
#pragma unroll
      for (int j = 0; j < 4; ++j) {
        ab[kk][j] = (__bf16)F[kk][0][j];
        ab[kk][4 + j] = (__bf16)F[kk][1][j];
      }
    f32x4 acc[8] = {};
#pragma unroll
    for (int kk = 0; kk < 4; ++kk)
#pragma unroll
      for (int n = 0; n < 8; ++n)
        acc[n] = __builtin_amdgcn_mfma_f32_16x16x32_bf16(
            *(const bf16x8*)(wl + (kk * 8 + n) * 512), ab[kk], acc[n], 0, 0, 0);
    __bf16* po = out + (size_t)row * 128;
#pragma unroll
    for (int n = 0; n < 8; ++n) {
      bf16x4 o;
#pragma unroll
      for (int j = 0; j < 4; ++j) o[j] = (__bf16)acc[n][j];
      *(bf16x4*)(po + n * 16 + q * 4) = o;
    }
  }
}

// Node MLP: K=256, A = x2 bf16 rows, resid = mesh.
__global__ __launch_bounds__(256) __attribute__((amdgpu_waves_per_eu(2, 4)))
void node_kernel(const __bf16* __restrict__ Ab, const float* __restrict__ W,
                 const float* __restrict__ gvec, const float* __restrict__ bvec,
                 const float* __restrict__ resid, float* __restrict__ out,
                 int M) {
  __shared__ __bf16 wt[4096 * 8];  // 64 KB
  stage_W<256>(W, wt);
  __syncthreads();
  const int tid = threadIdx.x, lane = tid & 63, wid = tid >> 6;
  const int r = lane & 15, q = lane >> 4;
  const __bf16* wl = wt + lane * 8;
  const int t = blockIdx.x * 4 + wid;
  if (t >= (M >> 4)) return;
  const int row = (t << 4) + r;
  const __bf16* pb = Ab + (size_t)row * 256 + q * 8;
  bf16x8 ab[8];
#pragma unroll
  for (int kk = 0; kk < 8; ++kk) ab[kk] = *(const bf16x8*)(pb + kk * 32);
  f32x4 R[8];
#pragma unroll
  for (int n = 0; n < 8; ++n)
    R[n] = *(const f32x4*)(resid + (size_t)row * 128 + n * 16 + q * 4);
  f32x4 acc[8] = {};
#pragma unroll
  for (int kk = 0; kk < 8; ++kk)
#pragma unroll
    for (int n = 0; n < 8; ++n)
      acc[n] = __builtin_amdgcn_mfma_f32_16x16x32_bf16(
          *(const bf16x8*)(wl + (kk * 8 + n) * 512), ab[kk], acc[n], 0, 0, 0);
  mlp_epilogue<false, false>(acc, R, gvec, bvec, q, out + (size_t)row * 128,
                             nullptr);
}

// Aggregation: x2[n] = concat(bf16(mesh[n]), bf16(mean_k coef*delta[eid[n][k]]))
template <bool FROM_WS>
__global__ __launch_bounds__(256) void agg_kernel(
    const __bf16* __restrict__ dws, const float* __restrict__ out0,
    const float* __restrict__ gm, const float* __restrict__ mesh,
    const int* __restrict__ eid, const float* __restrict__ coef,
    __bf16* __restrict__ x2) {
  __shared__ int eid_s[512];
  __shared__ float cf_s[512];
  const int t = threadIdx.x;
  const int n0 = blockIdx.x * 16;
  for (int i = t; i < 512; i += 256) {
    eid_s[i] = eid[n0 * 32 + i];
    cf_s[i] = coef[n0 * 32 + i];
  }
  __syncthreads();
  const int rl = t >> 4;
  const int d8 = (t & 15) * 8;
  const int row = n0 + rl;
  float acc[8] = {0, 0, 0, 0, 0, 0, 0, 0};
  for (int k = 0; k < 32; ++k) {
    const int e = eid_s[rl * 32 + k];
    const float cf = cf_s[rl * 32 + k];
    if (FROM_WS) {
      bf16x8 v = *(const bf16x8*)(dws + (size_t)e * 128 + d8);
#pragma unroll
      for (int j = 0; j < 8; ++j) acc[j] += cf * (float)v[j];
    } else {
      const float* po = out0 + (size_t)e * 128 + d8;
      const float* pg = gm + (size_t)e * 128 + d8;
      f32x4 o0 = *(const f32x4*)po, o1 = *(const f32x4*)(po + 4);
      f32x4 g0 = *(const f32x4*)pg, g1 = *(const f32x4*)(pg + 4);
#pragma unroll
      for (int j = 0; j < 4; ++j) {
        acc[j] += cf * (o0[j] - g0[j]);
        acc[4 + j] += cf * (o1[j] - g1[j]);
      }
    }
  }
  const float* pm = mesh + (size_t)row * 128 + d8;
  f32x4 m0 = *(const f32x4*)pm, m1 = *(const f32x4*)(pm + 4);
  bf16x8 mv, av;
#pragma unroll
  for (int j = 0; j < 4; ++j) {
    mv[j] = (__bf16)m0[j];
    mv[4 + j] = (__bf16)m1[j];
  }
#pragma unroll
  for (int j = 0; j < 8; ++j) av[j] = (__bf16)(acc[j] * (1.0f / 32.0f));
  *(bf16x8*)(x2 + (size_t)row * 256 + d8) = mv;
  *(bf16x8*)(x2 + (size_t)row * 256 + 128 + d8) = av;
}

extern "C" void kernel_launch(void* const* d_in, const int* in_sizes, int n_in,
                              void* d_out, int out_size, void* d_ws,
                              size_t ws_size, hipStream_t stream) {
  const float* gm = (const float*)d_in[0];
  const float* rect = (const float*)d_in[1];
  const float* mesh = (const float*)d_in[2];
  const int* pair = (const int*)d_in[3];
  const int* eid = (const int*)d_in[4];
  const float* coef = (const float*)d_in[5];
  const float* W1 = (const float*)d_in[6];
  const float* g1 = (const float*)d_in[7];
  const float* b1 = (const float*)d_in[8];
  const float* W2 = (const float*)d_in[9];
  const float* g2 = (const float*)d_in[10];
  const float* b2 = (const float*)d_in[11];
  const float* W3 = (const float*)d_in[12];
  const float* g3 = (const float*)d_in[13];
  const float* b3 = (const float*)d_in[14];

  float* out0 = (float*)d_out;
  float* out1 = out0 + (size_t)E_CNT * 128;
  float* out2 = out1 + (size_t)NG_CNT * 128;

  const size_t deltaE = (size_t)E_CNT * 128;  // bf16 elems
  const size_t x2E = (size_t)NM_CNT * 256;
  const size_t p1E = (size_t)NG_CNT * 128;
  const bool fastD = ws_size >= (deltaE + x2E) * 2;
  const bool fastP = ws_size >= (deltaE + x2E + p1E) * 2;

  __bf16* delta = (__bf16*)d_ws;
  __bf16* x2 = fastD ? delta + deltaE : (__bf16*)d_ws;
  __bf16* P1ws = delta + deltaE + x2E;
  __bf16* P2 = (__bf16*)out2;  // overwritten by node_kernel at the end

  const __bf16* P1;
  if (fastP) {
    rect_fused_kernel<<<256, 256, 0, stream>>>(rect, W1 + 128 * 128, W3, g3,
                                               b3, out1, P1ws, NG_CNT);
    P1 = P1ws;
  } else {
    lin_kernel<<<256, 256, 0, stream>>>(rect, W1 + 128 * 128, (__bf16*)out1,
                                        NG_CNT);
    P1 = (const __bf16*)out1;
  }
  lin_kernel<<<128, 256, 0, stream>>>(mesh, W1 + 256 * 128, P2, NM_CNT);

  if (fastD) {
    edge_kernel<true><<<1024, 256, 0, stream>>>(gm, pair, P1, P2, W1, g1, b1,
                                                out0, delta, E_CNT);
    agg_kernel<true><<<512, 256, 0, stream>>>(delta, nullptr, nullptr, mesh,
                                              eid, coef, x2);
  } else {
    edge_kernel<false><<<1024, 256, 0, stream>>>(gm, pair, P1, P2, W1, g1, b1,
                                                 out0, nullptr, E_CNT);
    agg_kernel<false><<<512, 256, 0, stream>>>(nullptr, out0, gm, mesh, eid,
                                               coef, x2);
  }
  if (!fastP) {  // rect MLP overwrites out1 only after edge consumed P1
    mlp128_kernel<<<256, 256, 0, stream>>>(rect, W3, g3, b3, out1, NG_CNT);
  }
  node_kernel<<<128, 256, 0, stream>>>(x2, W2, g2, b2, mesh, out2, NM_CNT);
}

// Round 6
// 226.285 us; speedup vs baseline: 1.9544x; 1.9544x over previous
//
#include <hip/hip_runtime.h>

// Grid2Mesh via linearity: edge_pre = gm.W1a + P1[src] + P2[dst],
// P1 = rect.W1b (fused into rect-MLP kernel), P2 = mesh.W1c.
// bf16 MFMA 16x16x32 swapped operands -> lane owns an output row.
// R6: all W pre-converted ONCE to fragment-layout bf16 (ws tail); kernels
// stage LDS with a straight 16B copy. Straight-line 2 tiles/wave (no
// loop-carried regs -> no spills; unified reg file: arch VGPR + AGPR share
// the cap, so no waves_per_eu caps anywhere). Gathers for both tiles issued
// up front; tile1 A-row loads hidden under tile0 MFMA+epilogue.

typedef __bf16 bf16x8 __attribute__((ext_vector_type(8)));
typedef __bf16 bf16x4 __attribute__((ext_vector_type(4)));
typedef float f32x4 __attribute__((ext_vector_type(4)));
typedef unsigned int u32x4 __attribute__((ext_vector_type(4)));

#define E_CNT 262144
#define NG_CNT 65536
#define NM_CNT 8192

// fragment-buffer element offsets (bf16 elems)
#define WF_A 0       // W1 rows   0..127 (gm part)
#define WF_B 16384   // W1 rows 128..255 (rect part)
#define WF_C 32768   // W1 rows 256..383 (mesh part)
#define WF_3 49152   // W3
#define WF_2 65536   // W2 (256x128)
#define WF_TOT 98304 // elems = 192 KB

__device__ __forceinline__ float fast_tanh(float x) {
  float e = __expf(2.f * x);
  return 1.f - 2.f / (1.f + e);
}

// One-time: convert W (f32 row-major) to fragment-layout bf16.
// chunk c=(kk*8+nn)*64+lane, lane=(qq*16+cx): holds W[kk*32+qq*8+j][nn*16+cx].
__global__ __launch_bounds__(256) void convert_w_kernel(
    const float* __restrict__ W1, const float* __restrict__ W2,
    const float* __restrict__ W3, __bf16* __restrict__ WF) {
  const int cid = blockIdx.x * 256 + threadIdx.x;  // 0..12287
  if (cid >= 12288) return;
  const float* src;
  __bf16* dst;
  int local;
  if (cid < 2048) { src = W1; local = cid; dst = WF + WF_A; }
  else if (cid < 4096) { src = W1 + 128 * 128; local = cid - 2048; dst = WF + WF_B; }
  else if (cid < 6144) { src = W1 + 256 * 128; local = cid - 4096; dst = WF + WF_C; }
  else if (cid < 8192) { src = W3; local = cid - 6144; dst = WF + WF_3; }
  else { src = W2; local = cid - 8192; dst = WF + WF_2; }
  const int lane6 = local & 63, cx = lane6 & 15, qq = lane6 >> 4;
  const int kkn = local >> 6, kk = kkn >> 3, nn = kkn & 7;
  const int k0 = kk * 32 + qq * 8, col = nn * 16 + cx;
  bf16x8 v;
#pragma unroll
  for (int j = 0; j < 8; ++j) v[j] = (__bf16)src[(k0 + j) * 128 + col];
  *(bf16x8*)(dst + local * 8) = v;
}

// straight 16B-granule LDS copy of a pre-built fragment buffer
__device__ __forceinline__ void stage_copy(const __bf16* __restrict__ wf,
                                           __bf16* wt, int nelems) {
  const int n16 = nelems >> 3;
  for (int i = threadIdx.x; i < n16; i += blockDim.x)
    *(u32x4*)(wt + i * 8) = *(const u32x4*)(wf + i * 8);
}

// tanh + LN + residual epilogue; acc[n][j] = pre[row][n*16+q*4+j].
template <bool STORE_D>
__device__ __forceinline__ void mlp_epilogue(f32x4* acc, const f32x4* R,
                                             const float* gvec,
                                             const float* bvec, int q,
                                             float* op, __bf16* dp) {
  float s1 = 0.f, s2 = 0.f;
#pragma unroll
  for (int n = 0; n < 8; ++n)
#pragma unroll
    for (int j = 0; j < 4; ++j) {
      float v = fast_tanh(acc[n][j]);
      acc[n][j] = v;
      s1 += v;
      s2 += v * v;
    }
  s1 += __shfl_xor(s1, 16, 64);
  s2 += __shfl_xor(s2, 16, 64);
  s1 += __shfl_xor(s1, 32, 64);
  s2 += __shfl_xor(s2, 32, 64);
  const float mu = s1 * (1.f / 128.f);
  const float rs = rsqrtf(s2 * (1.f / 128.f) - mu * mu + 1e-5f);
#pragma unroll
  for (int n = 0; n < 8; ++n) {
    const f32x4 G = *(const f32x4*)(gvec + n * 16 + q * 4);
    const f32x4 Bv = *(const f32x4*)(bvec + n * 16 + q * 4);
    f32x4 o;
    bf16x4 db;
#pragma unroll
    for (int j = 0; j < 4; ++j) {
      const float d = (acc[n][j] - mu) * rs * G[j] + Bv[j];
      o[j] = R[n][j] + d;
      db[j] = (__bf16)d;
    }
    *(f32x4*)(op + n * 16 + q * 4) = o;
    if (STORE_D) *(bf16x4*)(dp + n * 16 + q * 4) = db;
  }
}

// Edge: out0 = gm + LN(tanh(gm.W1a + P1[src] + P2[dst]))*g+b.
// Straight-line 2 tiles/wave; gathers for both tiles issued up front;
// tile1 A loads fly under tile0 MFMA+epilogue. grid = tiles/8.
template <bool STORE_D>
__global__ __launch_bounds__(256) void edge_kernel(
    const float* __restrict__ gm, const int* __restrict__ pair,
    const __bf16* __restrict__ P1, const __bf16* __restrict__ P2,
    const __bf16* __restrict__ WF, const float* __restrict__ gvec,
    const float* __restrict__ bvec, float* __restrict__ out,
    __bf16* __restrict__ delta_out) {
  __shared__ __bf16 wt[16384];  // 32 KB
  stage_copy(WF, wt, 16384);
  __syncthreads();
  const int tid = threadIdx.x, lane = tid & 63, wid = tid >> 6;
  const int r = lane & 15, q = lane >> 4;
  const __bf16* wl = wt + lane * 8;
  const int row0 = ((blockIdx.x * 8 + wid) << 4) + r;
  const int row1 = row0 + 64;  // tile t0+4

  // independent long-latency loads first
  const int2 sd0 = *(const int2*)(pair + 2 * (size_t)row0);
  const int2 sd1 = *(const int2*)(pair + 2 * (size_t)row1);
  const float* pa0 = gm + (size_t)row0 * 128;
  f32x4 F[4][2];
#pragma unroll
  for (int kk = 0; kk < 4; ++kk) {
    F[kk][0] = *(const f32x4*)(pa0 + kk * 32 + q * 8);
    F[kk][1] = *(const f32x4*)(pa0 + kk * 32 + q * 8 + 4);
  }
  bf16x4 gA1[8], gA2[8], gB1[8], gB2[8];
  {
    const __bf16* p1 = P1 + (size_t)sd0.x * 128 + q * 4;
    const __bf16* p2 = P2 + (size_t)sd0.y * 128 + q * 4;
#pragma unroll
    for (int n = 0; n < 8; ++n) {
      gA1[n] = *(const bf16x4*)(p1 + n * 16);
      gA2[n] = *(const bf16x4*)(p2 + n * 16);
    }
  }
  {
    const __bf16* p1 = P1 + (size_t)sd1.x * 128 + q * 4;
    const __bf16* p2 = P2 + (size_t)sd1.y * 128 + q * 4;
#pragma unroll
    for (int n = 0; n < 8; ++n) {
      gB1[n] = *(const bf16x4*)(p1 + n * 16);
      gB2[n] = *(const bf16x4*)(p2 + n * 16);
    }
  }
  // tile 0
  bf16x8 ab[4];
#pragma unroll
  for (int kk = 0; kk < 4; ++kk)
#pragma unroll
    for (int j = 0; j < 4; ++j) {
      ab[kk][j] = (__bf16)F[kk][0][j];
      ab[kk][4 + j] = (__bf16)F[kk][1][j];
    }
  // tile1 A loads: issue now, consumed after tile0 epilogue
  const float* pa1 = gm + (size_t)row1 * 128;
  f32x4 F1[4][2];
#pragma unroll
  for (int kk = 0; kk < 4; ++kk) {
    F1[kk][0] = *(const f32x4*)(pa1 + kk * 32 + q * 8);
    F1[kk][1] = *(const f32x4*)(pa1 + kk * 32 + q * 8 + 4);
  }
  f32x4 acc[8];
#pragma unroll
  for (int n = 0; n < 8; ++n)
#pragma unroll
    for (int j = 0; j < 4; ++j) acc[n][j] = (float)gA1[n][j] + (float)gA2[n][j];
#pragma unroll
  for (int kk = 0; kk < 4; ++kk)
#pragma unroll
    for (int n = 0; n < 8; ++n)
      acc[n] = __builtin_amdgcn_mfma_f32_16x16x32_bf16(
          *(const bf16x8*)(wl + (kk * 8 + n) * 512), ab[kk], acc[n], 0, 0, 0);
  f32x4 R[8];
#pragma unroll
  for (int n = 0; n < 8; ++n) R[n] = *(const f32x4*)(pa0 + n * 16 + q * 4);
  mlp_epilogue<STORE_D>(acc, R, gvec, bvec, q, out + (size_t)row0 * 128,
                        STORE_D ? delta_out + (size_t)row0 * 128 : nullptr);
  // tile 1
#pragma unroll
  for (int kk = 0; kk < 4; ++kk)
#pragma unroll
    for (int j = 0; j < 4; ++j) {
      ab[kk][j] = (__bf16)F1[kk][0][j];
      ab[kk][4 + j] = (__bf16)F1[kk][1][j];
    }
#pragma unroll
  for (int n = 0; n < 8; ++n)
#pragma unroll
    for (int j = 0; j < 4; ++j) acc[n][j] = (float)gB1[n][j] + (float)gB2[n][j];
#pragma unroll
  for (int kk = 0; kk < 4; ++kk)
#pragma unroll
    for (int n = 0; n < 8; ++n)
      acc[n] = __builtin_amdgcn_mfma_f32_16x16x32_bf16(
          *(const bf16x8*)(wl + (kk * 8 + n) * 512), ab[kk], acc[n], 0, 0, 0);
#pragma unroll
  for (int n = 0; n < 8; ++n) R[n] = *(const f32x4*)(pa1 + n * 16 + q * 4);
  mlp_epilogue<STORE_D>(acc, R, gvec, bvec, q, out + (size_t)row1 * 128,
                        STORE_D ? delta_out + (size_t)row1 * 128 : nullptr);
}

// Fused rect: P1 = bf16(rect.W1b) AND out1 = rect + mlp(rect, W3).
// 2 tiles/wave straight-line; grid = 4096/8 = 512.
__global__ __launch_bounds__(256) void rect_fused_kernel(
    const float* __restrict__ rect, const __bf16* __restrict__ WFb,
    const __bf16* __restrict__ WF3, const float* __restrict__ gvec,
    const float* __restrict__ bvec, float* __restrict__ out1,
    __bf16* __restrict__ P1) {
  __shared__ __bf16 wt[32768];  // 64 KB: [0]=W1b frags, [16384]=W3 frags
  stage_copy(WFb, wt, 16384);
  stage_copy(WF3, wt + 16384, 16384);
  __syncthreads();
  const int tid = threadIdx.x, lane = tid & 63, wid = tid >> 6;
  const int r = lane & 15, q = lane >> 4;
  const __bf16* wl = wt + lane * 8;
  const int row0 = ((blockIdx.x * 8 + wid) << 4) + r;
#pragma unroll 1
  for (int half = 0; half < 2; ++half) {
    const int row = row0 + half * 64;
    const float* pa = rect + (size_t)row * 128;
    f32x4 F[4][2];
#pragma unroll
    for (int kk = 0; kk < 4; ++kk) {
      F[kk][0] = *(const f32x4*)(pa + kk * 32 + q * 8);
      F[kk][1] = *(const f32x4*)(pa + kk * 32 + q * 8 + 4);
    }
    bf16x8 ab[4];
#pragma unroll
    for (int kk = 0; kk < 4; ++kk)
#pragma unroll
      for (int j = 0; j < 4; ++j) {
        ab[kk][j] = (__bf16)F[kk][0][j];
        ab[kk][4 + j] = (__bf16)F[kk][1][j];
      }
    f32x4 acc[8] = {};
#pragma unroll
    for (int kk = 0; kk < 4; ++kk)
#pragma unroll
      for (int n = 0; n < 8; ++n)
        acc[n] = __builtin_amdgcn_mfma_f32_16x16x32_bf16(
            *(const bf16x8*)(wl + (kk * 8 + n) * 512), ab[kk], acc[n], 0, 0, 0);
    __bf16* pp = P1 + (size_t)row * 128;
#pragma unroll
    for (int n = 0; n < 8; ++n) {
      bf16x4 o;
#pragma unroll
      for (int j = 0; j < 4; ++j) o[j] = (__bf16)acc[n][j];
      *(bf16x4*)(pp + n * 16 + q * 4) = o;
    }
    f32x4 acc2[8] = {};
#pragma unroll
    for (int kk = 0; kk < 4; ++kk)
#pragma unroll
      for (int n = 0; n < 8; ++n)
        acc2[n] = __builtin_amdgcn_mfma_f32_16x16x32_bf16(
            *(const bf16x8*)(wl + 16384 + (kk * 8 + n) * 512), ab[kk], acc2[n],
            0, 0, 0);
    f32x4 R[8];
#pragma unroll
    for (int n = 0; n < 8; ++n) R[n] = *(const f32x4*)(pa + n * 16 + q * 4);
    mlp_epilogue<false>(acc2, R, gvec, bvec, q, out1 + (size_t)row * 128,
                        nullptr);
  }
}

// Plain K=128 MLP (fallback rect path): out = A + mlp(A, W). 1 tile/wave.
__global__ __launch_bounds__(256) void mlp128_kernel(
    const float* __restrict__ A, const __bf16* __restrict__ WFx,
    const float* __restrict__ gvec, const float* __restrict__ bvec,
    float* __restrict__ out, int M) {
  __shared__ __bf16 wt[16384];
  stage_copy(WFx, wt, 16384);
  __syncthreads();
  const int tid = threadIdx.x, lane = tid & 63, wid = tid >> 6;
  const int r = lane & 15, q = lane >> 4;
  const __bf16* wl = wt + lane * 8;
  const int t = blockIdx.x * 4 + wid;
  if (t >= (M >> 4)) return;
  const int row = (t << 4) + r;
  const float* pa = A + (size_t)row * 128;
  f32x4 F[4][2];
#pragma unroll
  for (int kk = 0; kk < 4; ++kk) {
    F[kk][0] = *(const f32x4*)(pa + kk * 32 + q * 8);
    F[kk][1] = *(const f32x4*)(pa + kk * 32 + q * 8 + 4);
  }
  bf16x8 ab[4];
#pragma unroll
  for (int kk = 0; kk < 4; ++kk)
#pragma unroll
    for (int j = 0; j < 4; ++j) {
      ab[kk][j] = (__bf16)F[kk][0][j];
      ab[kk][4 + j] = (__bf16)F[kk][1][j];
    }
  f32x4 acc[8] = {};
#pragma unroll
  for (int kk = 0; kk < 4; ++kk)
#pragma unroll
    for (int n = 0; n < 8; ++n)
      acc[n] = __builtin_amdgcn_mfma_f32_16x16x32_bf16(
          *(const bf16x8*)(wl + (kk * 8 + n) * 512), ab[kk], acc[n], 0, 0, 0);
  f32x4 R[8];
#pragma unroll
  for (int n = 0; n < 8; ++n) R[n] = *(const f32x4*)(pa + n * 16 + q * 4);
  mlp_epilogue<false>(acc, R, gvec, bvec, q, out + (size_t)row * 128, nullptr);
}

// Dense K=128 linear, bf16 out (P2 / P1 fallback). 1 tile/wave.
__global__ __launch_bounds__(256) void lin_kernel(
    const float* __restrict__ A, const __bf16* __restrict__ WFx,
    __bf16* __restrict__ out, int M) {
  __shared__ __bf16 wt[16384];
  stage_copy(WFx, wt, 16384);
  __syncthreads();
  const int tid = threadIdx.x, lane = tid & 63, wid = tid >> 6;
  const int r = lane & 15, q = lane >> 4;
  const __bf16* wl = wt + lane * 8;
  const int t = blockIdx.x * 4 + wid;
  if (t >= (M >> 4)) return;
  const int row = (t << 4) + r;
  const float* pa = A + (size_t)row * 128;
  f32x4 F[4][2];
#pragma unroll
  for (int kk = 0; kk < 4; ++kk) {
    F[kk][0] = *(const f32x4*)(pa + kk * 32 + q * 8);
    F[kk][1] = *(const f32x4*)(pa + kk * 32 + q * 8 + 4);
  }
  bf16x8 ab[4];
#pragma unroll
  for (int kk = 0; kk < 4; ++kk)
#pragma unroll
    for (int j = 0; j < 4; ++j) {
      ab[kk][j] = (__bf16)F[kk][0][j];
      ab[kk][4 + j] = (__bf16)F[kk][1][j];
    }
  f32x4 acc[8] = {};
#pragma unroll
  for (int kk = 0; kk < 4; ++kk)
#pragma unroll
    for (int n = 0; n < 8; ++n)
      acc[n] = __builtin_amdgcn_mfma_f32_16x16x32_bf16(
          *(const bf16x8*)(wl + (kk * 8 + n) * 512), ab[kk], acc[n], 0, 0, 0);
  __bf16* po = out + (size_t)row * 128;
#pragma unroll
  for (int n = 0; n < 8; ++n) {
    bf16x4 o;
#pragma unroll
    for (int j = 0; j < 4; ++j) o[j] = (__bf16)acc[n][j];
    *(bf16x4*)(po + n * 16 + q * 4) = o;
  }
}

// Node MLP: K=256, A = x2 bf16 rows, resid = mesh. 1 tile/wave.
__global__ __launch_bounds__(256) void node_kernel(
    const __bf16* __restrict__ Ab, const __bf16* __restrict__ WF2,
    const float* __restrict__ gvec, const float* __restrict__ bvec,
    const float* __restrict__ resid, float* __restrict__ out, int M) {
  __shared__ __bf16 wt[32768];  // 64 KB
  stage_copy(WF2, wt, 32768);
  __syncthreads();
  const int tid = threadIdx.x, lane = tid & 63, wid = tid >> 6;
  const int r = lane & 15, q = lane >> 4;
  const __bf16* wl = wt + lane * 8;
  const int t = blockIdx.x * 4 + wid;
  if (t >= (M >> 4)) return;
  const int row = (t << 4) + r;
  const __bf16* pb = Ab + (size_t)row * 256 + q * 8;
  bf16x8 ab[8];
#pragma unroll
  for (int kk = 0; kk < 8; ++kk) ab[kk] = *(const bf16x8*)(pb + kk * 32);
  f32x4 R[8];
#pragma unroll
  for (int n = 0; n < 8; ++n)
    R[n] = *(const f32x4*)(resid + (size_t)row * 128 + n * 16 + q * 4);
  f32x4 acc[8] = {};
#pragma unroll
  for (int kk = 0; kk < 8; ++kk)
#pragma unroll
    for (int n = 0; n < 8; ++n)
      acc[n] = __builtin_amdgcn_mfma_f32_16x16x32_bf16(
          *(const bf16x8*)(wl + (kk * 8 + n) * 512), ab[kk], acc[n], 0, 0, 0);
  mlp_epilogue<false>(acc, R, gvec, bvec, q, out + (size_t)row * 128, nullptr);
}

// x2[n] = concat(bf16(mesh[n]), bf16(mean_k coef*delta[eid[n][k]]))
template <bool FROM_WS>
__global__ __launch_bounds__(256) void agg_kernel(
    const __bf16* __restrict__ dws, const float* __restrict__ out0,
    const float* __restrict__ gm, const float* __restrict__ mesh,
    const int* __restrict__ eid, const float* __restrict__ coef,
    __bf16* __restrict__ x2) {
  __shared__ int eid_s[512];
  __shared__ float cf_s[512];
  const int t = threadIdx.x;
  const int n0 = blockIdx.x * 16;
  for (int i = t; i < 512; i += 256) {
    eid_s[i] = eid[n0 * 32 + i];
    cf_s[i] = coef[n0 * 32 + i];
  }
  __syncthreads();
  const int rl = t >> 4;
  const int d8 = (t & 15) * 8;
  const int row = n0 + rl;
  float acc[8] = {0, 0, 0, 0, 0, 0, 0, 0};
  for (int k = 0; k < 32; ++k) {
    const int e = eid_s[rl * 32 + k];
    const float cf = cf_s[rl * 32 + k];
    if (FROM_WS) {
      bf16x8 v = *(const bf16x8*)(dws + (size_t)e * 128 + d8);
#pragma unroll
      for (int j = 0; j < 8; ++j) acc[j] += cf * (float)v[j];
    } else {
      const float* po = out0 + (size_t)e * 128 + d8;
      const float* pg = gm + (size_t)e * 128 + d8;
      f32x4 o0 = *(const f32x4*)po, o1 = *(const f32x4*)(po + 4);
      f32x4 g0 = *(const f32x4*)pg, g1 = *(const f32x4*)(pg + 4);
#pragma unroll
      for (int j = 0; j < 4; ++j) {
        acc[j] += cf * (o0[j] - g0[j]);
        acc[4 + j] += cf * (o1[j] - g1[j]);
      }
    }
  }
  const float* pm = mesh + (size_t)row * 128 + d8;
  f32x4 m0 = *(const f32x4*)pm, m1 = *(const f32x4*)(pm + 4);
  bf16x8 mv, av;
#pragma unroll
  for (int j = 0; j < 4; ++j) {
    mv[j] = (__bf16)m0[j];
    mv[4 + j] = (__bf16)m1[j];
  }
#pragma unroll
  for (int j = 0; j < 8; ++j) av[j] = (__bf16)(acc[j] * (1.0f / 32.0f));
  *(bf16x8*)(x2 + (size_t)row * 256 + d8) = mv;
  *(bf16x8*)(x2 + (size_t)row * 256 + 128 + d8) = av;
}

extern "C" void kernel_launch(void* const* d_in, const int* in_sizes, int n_in,
                              void* d_out, int out_size, void* d_ws,
                              size_t ws_size, hipStream_t stream) {
  const float* gm = (const float*)d_in[0];
  const float* rect = (const float*)d_in[1];
  const float* mesh = (const float*)d_in[2];
  const int* pair = (const int*)d_in[3];
  const int* eid = (const int*)d_in[4];
  const float* coef = (const float*)d_in[5];
  const float* W1 = (const float*)d_in[6];
  const float* g1 = (const float*)d_in[7];
  const float* b1 = (const float*)d_in[8];
  const float* W2 = (const float*)d_in[9];
  const float* g2 = (const float*)d_in[10];
  const float* b2 = (const float*)d_in[11];
  const float* W3 = (const float*)d_in[12];
  const float* g3 = (const float*)d_in[13];
  const float* b3 = (const float*)d_in[14];

  float* out0 = (float*)d_out;
  float* out1 = out0 + (size_t)E_CNT * 128;
  float* out2 = out1 + (size_t)NG_CNT * 128;

  // fragment buffer at the tail of ws (192 KB, 64B-aligned)
  const size_t wfBytes = (size_t)WF_TOT * 2;
  const size_t wfoff = (ws_size - wfBytes) & ~(size_t)63;
  __bf16* WF = (__bf16*)((char*)d_ws + wfoff);

  const size_t deltaE = (size_t)E_CNT * 128;  // bf16 elems
  const size_t x2E = (size_t)NM_CNT * 256;
  const size_t p1E = (size_t)NG_CNT * 128;
  const bool fastD = wfoff >= (deltaE + x2E) * 2;
  const bool fastP = wfoff >= (deltaE + x2E + p1E) * 2;

  __bf16* delta = (__bf16*)d_ws;
  __bf16* x2 = fastD ? delta + deltaE : (__bf16*)d_ws;
  __bf16* P1ws = delta + deltaE + x2E;
  __bf16* P2 = (__bf16*)out2;  // overwritten by node_kernel at the end

  convert_w_kernel<<<48, 256, 0, stream>>>(W1, W2, W3, WF);

  const __bf16* P1;
  if (fastP) {
    rect_fused_kernel<<<512, 256, 0, stream>>>(rect, WF + WF_B, WF + WF_3, g3,
                                               b3, out1, P1ws);
    P1 = P1ws;
  } else {
    lin_kernel<<<1024, 256, 0, stream>>>(rect, WF + WF_B, (__bf16*)out1,
                                         NG_CNT);
    P1 = (const __bf16*)out1;
  }
  lin_kernel<<<128, 256, 0, stream>>>(mesh, WF + WF_C, P2, NM_CNT);

  if (fastD) {
    edge_kernel<true><<<2048, 256, 0, stream>>>(gm, pair, P1, P2, WF + WF_A,
                                                g1, b1, out0, delta);
    agg_kernel<true><<<512, 256, 0, stream>>>(delta, nullptr, nullptr, mesh,
                                              eid, coef, x2);
  } else {
    edge_kernel<false><<<2048, 256, 0, stream>>>(gm, pair, P1, P2, WF + WF_A,
                                                 g1, b1, out0, nullptr);
    agg_kernel<false><<<512, 256, 0, stream>>>(nullptr, out0, gm, mesh, eid,
                                               coef, x2);
  }
  if (!fastP) {  // rect MLP overwrites out1 only after edge consumed P1
    mlp128_kernel<<<1024, 256, 0, stream>>>(rect, WF + WF_3, g3, b3, out1,
                                            NG_CNT);
  }
  node_kernel<<<128, 256, 0, stream>>>(x2, WF + WF_2, g2, b2, mesh, out2,
                                       NM_CNT);
}

// Round 7
// 204.747 us; speedup vs baseline: 2.1599x; 1.1052x over previous
//
#include <hip/hip_runtime.h>

// Grid2Mesh via linearity: edge_pre = gm.W1a + P1[src] + P2[dst],
// P1 = rect.W1b (fused into rect-MLP kernel), P2 = mesh.W1c.
// bf16 MFMA 16x16x32 swapped operands -> lane owns an output row.
// R7: edge back to 1 tile/wave (minimal live set), P-add moved POST-MFMA so
// the pair->gather chain never gates the MFMAs, __launch_bounds__(256,3)
// (170-reg unified cap; live set ~143 -> no spill, 3 waves/SIMD).
// W pre-converted once to fragment-layout bf16; LDS staged via 16B copies.

typedef __bf16 bf16x8 __attribute__((ext_vector_type(8)));
typedef __bf16 bf16x4 __attribute__((ext_vector_type(4)));
typedef float f32x4 __attribute__((ext_vector_type(4)));
typedef unsigned int u32x4 __attribute__((ext_vector_type(4)));

#define E_CNT 262144
#define NG_CNT 65536
#define NM_CNT 8192

// fragment-buffer element offsets (bf16 elems)
#define WF_A 0       // W1 rows   0..127 (gm part)
#define WF_B 16384   // W1 rows 128..255 (rect part)
#define WF_C 32768   // W1 rows 256..383 (mesh part)
#define WF_3 49152   // W3
#define WF_2 65536   // W2 (256x128)
#define WF_TOT 98304 // elems = 192 KB

__device__ __forceinline__ float fast_tanh(float x) {
  float e = __expf(2.f * x);
  return 1.f - 2.f / (1.f + e);
}

// One-time: convert W (f32 row-major) to fragment-layout bf16.
// chunk c=(kk*8+nn)*64+lane, lane=(qq*16+cx): holds W[kk*32+qq*8+j][nn*16+cx].
__global__ __launch_bounds__(256) void convert_w_kernel(
    const float* __restrict__ W1, const float* __restrict__ W2,
    const float* __restrict__ W3, __bf16* __restrict__ WF) {
  const int cid = blockIdx.x * 256 + threadIdx.x;  // 0..12287
  if (cid >= 12288) return;
  const float* src;
  __bf16* dst;
  int local;
  if (cid < 2048) { src = W1; local = cid; dst = WF + WF_A; }
  else if (cid < 4096) { src = W1 + 128 * 128; local = cid - 2048; dst = WF + WF_B; }
  else if (cid < 6144) { src = W1 + 256 * 128; local = cid - 4096; dst = WF + WF_C; }
  else if (cid < 8192) { src = W3; local = cid - 6144; dst = WF + WF_3; }
  else { src = W2; local = cid - 8192; dst = WF + WF_2; }
  const int lane6 = local & 63, cx = lane6 & 15, qq = lane6 >> 4;
  const int kkn = local >> 6, kk = kkn >> 3, nn = kkn & 7;
  const int k0 = kk * 32 + qq * 8, col = nn * 16 + cx;
  bf16x8 v;
#pragma unroll
  for (int j = 0; j < 8; ++j) v[j] = (__bf16)src[(k0 + j) * 128 + col];
  *(bf16x8*)(dst + local * 8) = v;
}

// straight 16B-granule LDS copy of a pre-built fragment buffer
__device__ __forceinline__ void stage_copy(const __bf16* __restrict__ wf,
                                           __bf16* wt, int nelems) {
  const int n16 = nelems >> 3;
  for (int i = threadIdx.x; i < n16; i += blockDim.x)
    *(u32x4*)(wt + i * 8) = *(const u32x4*)(wf + i * 8);
}

// tanh + LN + residual epilogue; acc[n][j] = pre[row][n*16+q*4+j].
template <bool STORE_D>
__device__ __forceinline__ void mlp_epilogue(f32x4* acc, const f32x4* R,
                                             const float* gvec,
                                             const float* bvec, int q,
                                             float* op, __bf16* dp) {
  float s1 = 0.f, s2 = 0.f;
#pragma unroll
  for (int n = 0; n < 8; ++n)
#pragma unroll
    for (int j = 0; j < 4; ++j) {
      float v = fast_tanh(acc[n][j]);
      acc[n][j] = v;
      s1 += v;
      s2 += v * v;
    }
  s1 += __shfl_xor(s1, 16, 64);
  s2 += __shfl_xor(s2, 16, 64);
  s1 += __shfl_xor(s1, 32, 64);
  s2 += __shfl_xor(s2, 32, 64);
  const float mu = s1 * (1.f / 128.f);
  const float rs = rsqrtf(s2 * (1.f / 128.f) - mu * mu + 1e-5f);
#pragma unroll
  for (int n = 0; n < 8; ++n) {
    const f32x4 G = *(const f32x4*)(gvec + n * 16 + q * 4);
    const f32x4 Bv = *(const f32x4*)(bvec + n * 16 + q * 4);
    f32x4 o;
    bf16x4 db;
#pragma unroll
    for (int j = 0; j < 4; ++j) {
      const float d = (acc[n][j] - mu) * rs * G[j] + Bv[j];
      o[j] = R[n][j] + d;
      db[j] = (__bf16)d;
    }
    *(f32x4*)(op + n * 16 + q * 4) = o;
    if (STORE_D) *(bf16x4*)(dp + n * 16 + q * 4) = db;
  }
}

// Edge: out0 = gm + LN(tanh(gm.W1a + P1[src] + P2[dst]))*g+b. 1 tile/wave.
// acc zero-init; MFMA gated only by contiguous F loads; gathers land any time
// before the post-MFMA add. 3 waves/SIMD via launch_bounds cap (no loops ->
// no loop-carried regs -> should fit 170 without spilling).
template <bool STORE_D>
__global__ __launch_bounds__(256, 3) void edge_kernel(
    const float* __restrict__ gm, const int* __restrict__ pair,
    const __bf16* __restrict__ P1, const __bf16* __restrict__ P2,
    const __bf16* __restrict__ WF, const float* __restrict__ gvec,
    const float* __restrict__ bvec, float* __restrict__ out,
    __bf16* __restrict__ delta_out) {
  __shared__ __bf16 wt[16384];  // 32 KB
  stage_copy(WF, wt, 16384);
  __syncthreads();
  const int tid = threadIdx.x, lane = tid & 63, wid = tid >> 6;
  const int r = lane & 15, q = lane >> 4;
  const __bf16* wl = wt + lane * 8;
  const int row = ((blockIdx.x * 4 + wid) << 4) + r;

  // independent long-latency loads first
  const int2 sd = *(const int2*)(pair + 2 * (size_t)row);
  const float* pa = gm + (size_t)row * 128;
  f32x4 F[4][2];
#pragma unroll
  for (int kk = 0; kk < 4; ++kk) {
    F[kk][0] = *(const f32x4*)(pa + kk * 32 + q * 8);
    F[kk][1] = *(const f32x4*)(pa + kk * 32 + q * 8 + 4);
  }
  // gathers (single dependent hop on sd); consumed only after MFMA
  bf16x4 pg1[8], pg2[8];
  {
    const __bf16* p1 = P1 + (size_t)sd.x * 128 + q * 4;
    const __bf16* p2 = P2 + (size_t)sd.y * 128 + q * 4;
#pragma unroll
    for (int n = 0; n < 8; ++n) {
      pg1[n] = *(const bf16x4*)(p1 + n * 16);
      pg2[n] = *(const bf16x4*)(p2 + n * 16);
    }
  }
  // residual row (independent, issued early, consumed last)
  f32x4 R[8];
#pragma unroll
  for (int n = 0; n < 8; ++n) R[n] = *(const f32x4*)(pa + n * 16 + q * 4);

  bf16x8 ab[4];
#pragma unroll
  for (int kk = 0; kk < 4; ++kk)
#pragma unroll
    for (int j = 0; j < 4; ++j) {
      ab[kk][j] = (__bf16)F[kk][0][j];
      ab[kk][4 + j] = (__bf16)F[kk][1][j];
    }
  f32x4 acc[8] = {};
#pragma unroll
  for (int kk = 0; kk < 4; ++kk)
#pragma unroll
    for (int n = 0; n < 8; ++n)
      acc[n] = __builtin_amdgcn_mfma_f32_16x16x32_bf16(
          *(const bf16x8*)(wl + (kk * 8 + n) * 512), ab[kk], acc[n], 0, 0, 0);
  // post-MFMA gather add
#pragma unroll
  for (int n = 0; n < 8; ++n)
#pragma unroll
    for (int j = 0; j < 4; ++j)
      acc[n][j] += (float)pg1[n][j] + (float)pg2[n][j];

  mlp_epilogue<STORE_D>(acc, R, gvec, bvec, q, out + (size_t)row * 128,
                        STORE_D ? delta_out + (size_t)row * 128 : nullptr);
}

// Fused rect: P1 = bf16(rect.W1b) AND out1 = rect + mlp(rect, W3).
// 2 tiles/wave straight-line; grid = 4096/8 = 512 (LDS 64KB caps blocks).
__global__ __launch_bounds__(256) void rect_fused_kernel(
    const float* __restrict__ rect, const __bf16* __restrict__ WFb,
    const __bf16* __restrict__ WF3, const float* __restrict__ gvec,
    const float* __restrict__ bvec, float* __restrict__ out1,
    __bf16* __restrict__ P1) {
  __shared__ __bf16 wt[32768];  // 64 KB: [0]=W1b frags, [16384]=W3 frags
  stage_copy(WFb, wt, 16384);
  stage_copy(WF3, wt + 16384, 16384);
  __syncthreads();
  const int tid = threadIdx.x, lane = tid & 63, wid = tid >> 6;
  const int r = lane & 15, q = lane >> 4;
  const __bf16* wl = wt + lane * 8;
  const int row0 = ((blockIdx.x * 8 + wid) << 4) + r;
#pragma unroll 1
  for (int half = 0; half < 2; ++half) {
    const int row = row0 + half * 64;
    const float* pa = rect + (size_t)row * 128;
    f32x4 F[4][2];
#pragma unroll
    for (int kk = 0; kk < 4; ++kk) {
      F[kk][0] = *(const f32x4*)(pa + kk * 32 + q * 8);
      F[kk][1] = *(const f32x4*)(pa + kk * 32 + q * 8 + 4);
    }
    bf16x8 ab[4];
#pragma unroll
    for (int kk = 0; kk < 4; ++kk)
#pragma unroll
      for (int j = 0; j < 4; ++j) {
        ab[kk][j] = (__bf16)F[kk][0][j];
        ab[kk][4 + j] = (__bf16)F[kk][1][j];
      }
    f32x4 acc[8] = {};
#pragma unroll
    for (int kk = 0; kk < 4; ++kk)
#pragma unroll
      for (int n = 0; n < 8; ++n)
        acc[n] = __builtin_amdgcn_mfma_f32_16x16x32_bf16(
            *(const bf16x8*)(wl + (kk * 8 + n) * 512), ab[kk], acc[n], 0, 0, 0);
    __bf16* pp = P1 + (size_t)row * 128;
#pragma unroll
    for (int n = 0; n < 8; ++n) {
      bf16x4 o;
#pragma unroll
      for (int j = 0; j < 4; ++j) o[j] = (__bf16)acc[n][j];
      *(bf16x4*)(pp + n * 16 + q * 4) = o;
    }
    f32x4 acc2[8] = {};
#pragma unroll
    for (int kk = 0; kk < 4; ++kk)
#pragma unroll
      for (int n = 0; n < 8; ++n)
        acc2[n] = __builtin_amdgcn_mfma_f32_16x16x32_bf16(
            *(const bf16x8*)(wl + 16384 + (kk * 8 + n) * 512), ab[kk], acc2[n],
            0, 0, 0);
    f32x4 R[8];
#pragma unroll
    for (int n = 0; n < 8; ++n) R[n] = *(const f32x4*)(pa + n * 16 + q * 4);
    mlp_epilogue<false>(acc2, R, gvec, bvec, q, out1 + (size_t)row * 128,
                        nullptr);
  }
}

// Plain K=128 MLP (fallback rect path): out = A + mlp(A, W). 1 tile/wave.
__global__ __launch_bounds__(256) void mlp128_kernel(
    const float* __restrict__ A, const __bf16* __restrict__ WFx,
    const float* __restrict__ gvec, const float* __restrict__ bvec,
    float* __restrict__ out, int M) {
  __shared__ __bf16 wt[16384];
  stage_copy(WFx, wt, 16384);
  __syncthreads();
  const int tid = threadIdx.x, lane = tid & 63, wid = tid >> 6;
  const int r = lane & 15, q = lane >> 4;
  const __bf16* wl = wt + lane * 8;
  const int t = blockIdx.x * 4 + wid;
  if (t >= (M >> 4)) return;
  const int row = (t << 4) + r;
  const float* pa = A + (size_t)row * 128;
  f32x4 F[4][2];
#pragma unroll
  for (int kk = 0; kk < 4; ++kk) {
    F[kk][0] = *(const f32x4*)(pa + kk * 32 + q * 8);
    F[kk][1] = *(const f32x4*)(pa + kk * 32 + q * 8 + 4);
  }
  bf16x8 ab[4];
#pragma unroll
  for (int kk = 0; kk < 4; ++kk)
#pragma unroll
    for (int j = 0; j < 4; ++j) {
      ab[kk][j] = (__bf16)F[kk][0][j];
      ab[kk][4 + j] = (__bf16)F[kk][1][j];
    }
  f32x4 acc[8] = {};
#pragma unroll
  for (int kk = 0; kk < 4; ++kk)
#pragma unroll
    for (int n = 0; n < 8; ++n)
      acc[n] = __builtin_amdgcn_mfma_f32_16x16x32_bf16(
          *(const bf16x8*)(wl + (kk * 8 + n) * 512), ab[kk], acc[n], 0, 0, 0);
  f32x4 R[8];
#pragma unroll
  for (int n = 0; n < 8; ++n) R[n] = *(const f32x4*)(pa + n * 16 + q * 4);
  mlp_epilogue<false>(acc, R, gvec, bvec, q, out + (size_t)row * 128, nullptr);
}

// Dense K=128 linear, bf16 out (P2 / P1 fallback). 1 tile/wave.
__global__ __launch_bounds__(256) void lin_kernel(
    const float* __restrict__ A, const __bf16* __restrict__ WFx,
    __bf16* __restrict__ out, int M) {
  __shared__ __bf16 wt[16384];
  stage_copy(WFx, wt, 16384);
  __syncthreads();
  const int tid = threadIdx.x, lane = tid & 63, wid = tid >> 6;
  const int r = lane & 15, q = lane >> 4;
  const __bf16* wl = wt + lane * 8;
  const int t = blockIdx.x * 4 + wid;
  if (t >= (M >> 4)) return;
  const int row = (t << 4) + r;
  const float* pa = A + (size_t)row * 128;
  f32x4 F[4][2];
#pragma unroll
  for (int kk = 0; kk < 4; ++kk) {
    F[kk][0] = *(const f32x4*)(pa + kk * 32 + q * 8);
    F[kk][1] = *(const f32x4*)(pa + kk * 32 + q * 8 + 4);
  }
  bf16x8 ab[4];
#pragma unroll
  for (int kk = 0; kk < 4; ++kk)
#pragma unroll
    for (int j = 0; j < 4; ++j) {
      ab[kk][j] = (__bf16)F[kk][0][j];
      ab[kk][4 + j] = (__bf16)F[kk][1][j];
    }
  f32x4 acc[8] = {};
#pragma unroll
  for (int kk = 0; kk < 4; ++kk)
#pragma unroll
    for (int n = 0; n < 8; ++n)
      acc[n] = __builtin_amdgcn_mfma_f32_16x16x32_bf16(
          *(const bf16x8*)(wl + (kk * 8 + n) * 512), ab[kk], acc[n], 0, 0, 0);
  __bf16* po = out + (size_t)row * 128;
#pragma unroll
  for (int n = 0; n < 8; ++n) {
    bf16x4 o;
#pragma unroll
    for (int j = 0; j < 4; ++j) o[j] = (__bf16)acc[n][j];
    *(bf16x4*)(po + n * 16 + q * 4) = o;
  }
}

// Node MLP: K=256, A = x2 bf16 rows, resid = mesh. 1 tile/wave.
__global__ __launch_bounds__(256) void node_kernel(
    const __bf16* __restrict__ Ab, const __bf16* __restrict__ WF2,
    const float* __restrict__ gvec, const float* __restrict__ bvec,
    const float* __restrict__ resid, float* __restrict__ out, int M) {
  __shared__ __bf16 wt[32768];  // 64 KB
  stage_copy(WF2, wt, 32768);
  __syncthreads();
  const int tid = threadIdx.x, lane = tid & 63, wid = tid >> 6;
  const int r = lane & 15, q = lane >> 4;
  const __bf16* wl = wt + lane * 8;
  const int t = blockIdx.x * 4 + wid;
  if (t >= (M >> 4)) return;
  const int row = (t << 4) + r;
  const __bf16* pb = Ab + (size_t)row * 256 + q * 8;
  bf16x8 ab[8];
#pragma unroll
  for (int kk = 0; kk < 8; ++kk) ab[kk] = *(const bf16x8*)(pb + kk * 32);
  f32x4 R[8];
#pragma unroll
  for (int n = 0; n < 8; ++n)
    R[n] = *(const f32x4*)(resid + (size_t)row * 128 + n * 16 + q * 4);
  f32x4 acc[8] = {};
#pragma unroll
  for (int kk = 0; kk < 8; ++kk)
#pragma unroll
    for (int n = 0; n < 8; ++n)
      acc[n] = __builtin_amdgcn_mfma_f32_16x16x32_bf16(
          *(const bf16x8*)(wl + (kk * 8 + n) * 512), ab[kk], acc[n], 0, 0, 0);
  mlp_epilogue<false>(acc, R, gvec, bvec, q, out + (size_t)row * 128, nullptr);
}

// x2[n] = concat(bf16(mesh[n]), bf16(mean_k coef*delta[eid[n][k]]))
template <bool FROM_WS>
__global__ __launch_bounds__(256) void agg_kernel(
    const __bf16* __restrict__ dws, const float* __restrict__ out0,
    const float* __restrict__ gm, const float* __restrict__ mesh,
    const int* __restrict__ eid, const float* __restrict__ coef,
    __bf16* __restrict__ x2) {
  __shared__ int eid_s[512];
  __shared__ float cf_s[512];
  const int t = threadIdx.x;
  const int n0 = blockIdx.x * 16;
  for (int i = t; i < 512; i += 256) {
    eid_s[i] = eid[n0 * 32 + i];
    cf_s[i] = coef[n0 * 32 + i];
  }
  __syncthreads();
  const int rl = t >> 4;
  const int d8 = (t & 15) * 8;
  const int row = n0 + rl;
  float acc[8] = {0, 0, 0, 0, 0, 0, 0, 0};
  for (int k = 0; k < 32; ++k) {
    const int e = eid_s[rl * 32 + k];
    const float cf = cf_s[rl * 32 + k];
    if (FROM_WS) {
      bf16x8 v = *(const bf16x8*)(dws + (size_t)e * 128 + d8);
#pragma unroll
      for (int j = 0; j < 8; ++j) acc[j] += cf * (float)v[j];
    } else {
      const float* po = out0 + (size_t)e * 128 + d8;
      const float* pg = gm + (size_t)e * 128 + d8;
      f32x4 o0 = *(const f32x4*)po, o1 = *(const f32x4*)(po + 4);
      f32x4 g0 = *(const f32x4*)pg, g1 = *(const f32x4*)(pg + 4);
#pragma unroll
      for (int j = 0; j < 4; ++j) {
        acc[j] += cf * (o0[j] - g0[j]);
        acc[4 + j] += cf * (o1[j] - g1[j]);
      }
    }
  }
  const float* pm = mesh + (size_t)row * 128 + d8;
  f32x4 m0 = *(const f32x4*)pm, m1 = *(const f32x4*)(pm + 4);
  bf16x8 mv, av;
#pragma unroll
  for (int j = 0; j < 4; ++j) {
    mv[j] = (__bf16)m0[j];
    mv[4 + j] = (__bf16)m1[j];
  }
#pragma unroll
  for (int j = 0; j < 8; ++j) av[j] = (__bf16)(acc[j] * (1.0f / 32.0f));
  *(bf16x8*)(x2 + (size_t)row * 256 + d8) = mv;
  *(bf16x8*)(x2 + (size_t)row * 256 + 128 + d8) = av;
}

extern "C" void kernel_launch(void* const* d_in, const int* in_sizes, int n_in,
                              void* d_out, int out_size, void* d_ws,
                              size_t ws_size, hipStream_t stream) {
  const float* gm = (const float*)d_in[0];
  const float* rect = (const float*)d_in[1];
  const float* mesh = (const float*)d_in[2];
  const int* pair = (const int*)d_in[3];
  const int* eid = (const int*)d_in[4];
  const float* coef = (const float*)d_in[5];
  const float* W1 = (const float*)d_in[6];
  const float* g1 = (const float*)d_in[7];
  const float* b1 = (const float*)d_in[8];
  const float* W2 = (const float*)d_in[9];
  const float* g2 = (const float*)d_in[10];
  const float* b2 = (const float*)d_in[11];
  const float* W3 = (const float*)d_in[12];
  const float* g3 = (const float*)d_in[13];
  const float* b3 = (const float*)d_in[14];

  float* out0 = (float*)d_out;
  float* out1 = out0 + (size_t)E_CNT * 128;
  float* out2 = out1 + (size_t)NG_CNT * 128;

  // fragment buffer at the tail of ws (192 KB, 64B-aligned)
  const size_t wfBytes = (size_t)WF_TOT * 2;
  const size_t wfoff = (ws_size - wfBytes) & ~(size_t)63;
  __bf16* WF = (__bf16*)((char*)d_ws + wfoff);

  const size_t deltaE = (size_t)E_CNT * 128;  // bf16 elems
  const size_t x2E = (size_t)NM_CNT * 256;
  const size_t p1E = (size_t)NG_CNT * 128;
  const bool fastD = wfoff >= (deltaE + x2E) * 2;
  const bool fastP = wfoff >= (deltaE + x2E + p1E) * 2;

  __bf16* delta = (__bf16*)d_ws;
  __bf16* x2 = fastD ? delta + deltaE : (__bf16*)d_ws;
  __bf16* P1ws = delta + deltaE + x2E;
  __bf16* P2 = (__bf16*)out2;  // overwritten by node_kernel at the end

  convert_w_kernel<<<48, 256, 0, stream>>>(W1, W2, W3, WF);

  const __bf16* P1;
  if (fastP) {
    rect_fused_kernel<<<512, 256, 0, stream>>>(rect, WF + WF_B, WF + WF_3, g3,
                                               b3, out1, P1ws);
    P1 = P1ws;
  } else {
    lin_kernel<<<1024, 256, 0, stream>>>(rect, WF + WF_B, (__bf16*)out1,
                                         NG_CNT);
    P1 = (const __bf16*)out1;
  }
  lin_kernel<<<128, 256, 0, stream>>>(mesh, WF + WF_C, P2, NM_CNT);

  if (fastD) {
    edge_kernel<true><<<4096, 256, 0, stream>>>(gm, pair, P1, P2, WF + WF_A,
                                                g1, b1, out0, delta);
    agg_kernel<true><<<512, 256, 0, stream>>>(delta, nullptr, nullptr, mesh,
                                              eid, coef, x2);
  } else {
    edge_kernel<false><<<4096, 256, 0, stream>>>(gm, pair, P1, P2, WF + WF_A,
                                                 g1, b1, out0, nullptr);
    agg_kernel<false><<<512, 256, 0, stream>>>(nullptr, out0, gm, mesh, eid,
                                               coef, x2);
  }
  if (!fastP) {  // rect MLP overwrites out1 only after edge consumed P1
    mlp128_kernel<<<1024, 256, 0, stream>>>(rect, WF + WF_3, g3, b3, out1,
                                            NG_CNT);
  }
  node_kernel<<<128, 256, 0, stream>>>(x2, WF + WF_2, g2, b2, mesh, out2,
                                       NM_CNT);
}

// Round 8
// 185.243 us; speedup vs baseline: 2.3874x; 1.1053x over previous
//
#include <hip/hip_runtime.h>

// Grid2Mesh via linearity: edge_pre = gm.W1a + P1[src] + P2[dst],
// P1 = rect.W1b (fused into rect-MLP kernel), P2 = mesh.W1c.
// bf16 MFMA 16x16x32 swapped operands -> lane owns an output row.
// R8: NO LDS anywhere. W fragments read directly from global WF buffer
// (32 KB = L1-sized, L2-hot, perfectly coalesced 1KB/instr). No staging
// prologue, no barrier, no LDS occupancy cap -> waves limited by regs only.
// NT stores on final outputs; agg gather loop unrolled 8x.

typedef __bf16 bf16x8 __attribute__((ext_vector_type(8)));
typedef __bf16 bf16x4 __attribute__((ext_vector_type(4)));
typedef float f32x4 __attribute__((ext_vector_type(4)));

#define E_CNT 262144
#define NG_CNT 65536
#define NM_CNT 8192

// fragment-buffer element offsets (bf16 elems)
#define WF_A 0       // W1 rows   0..127 (gm part)
#define WF_B 16384   // W1 rows 128..255 (rect part)
#define WF_C 32768   // W1 rows 256..383 (mesh part)
#define WF_3 49152   // W3
#define WF_2 65536   // W2 (256x128)
#define WF_TOT 98304 // elems = 192 KB

__device__ __forceinline__ float fast_tanh(float x) {
  float e = __expf(2.f * x);
  return 1.f - 2.f / (1.f + e);
}

// One-time: convert W (f32 row-major) to fragment-layout bf16.
// chunk c=(kk*8+nn)*64+lane, lane=(qq*16+cx): holds W[kk*32+qq*8+j][nn*16+cx].
__global__ __launch_bounds__(256) void convert_w_kernel(
    const float* __restrict__ W1, const float* __restrict__ W2,
    const float* __restrict__ W3, __bf16* __restrict__ WF) {
  const int cid = blockIdx.x * 256 + threadIdx.x;  // 0..12287
  if (cid >= 12288) return;
  const float* src;
  __bf16* dst;
  int local;
  if (cid < 2048) { src = W1; local = cid; dst = WF + WF_A; }
  else if (cid < 4096) { src = W1 + 128 * 128; local = cid - 2048; dst = WF + WF_B; }
  else if (cid < 6144) { src = W1 + 256 * 128; local = cid - 4096; dst = WF + WF_C; }
  else if (cid < 8192) { src = W3; local = cid - 6144; dst = WF + WF_3; }
  else { src = W2; local = cid - 8192; dst = WF + WF_2; }
  const int lane6 = local & 63, cx = lane6 & 15, qq = lane6 >> 4;
  const int kkn = local >> 6, kk = kkn >> 3, nn = kkn & 7;
  const int k0 = kk * 32 + qq * 8, col = nn * 16 + cx;
  bf16x8 v;
#pragma unroll
  for (int j = 0; j < 8; ++j) v[j] = (__bf16)src[(k0 + j) * 128 + col];
  *(bf16x8*)(dst + local * 8) = v;
}

// tanh + LN + residual epilogue; acc[n][j] = pre[row][n*16+q*4+j].
template <bool STORE_D, bool NT>
__device__ __forceinline__ void mlp_epilogue(f32x4* acc, const f32x4* R,
                                             const float* gvec,
                                             const float* bvec, int q,
                                             float* op, __bf16* dp) {
  float s1 = 0.f, s2 = 0.f;
#pragma unroll
  for (int n = 0; n < 8; ++n)
#pragma unroll
    for (int j = 0; j < 4; ++j) {
      float v = fast_tanh(acc[n][j]);
      acc[n][j] = v;
      s1 += v;
      s2 += v * v;
    }
  s1 += __shfl_xor(s1, 16, 64);
  s2 += __shfl_xor(s2, 16, 64);
  s1 += __shfl_xor(s1, 32, 64);
  s2 += __shfl_xor(s2, 32, 64);
  const float mu = s1 * (1.f / 128.f);
  const float rs = rsqrtf(s2 * (1.f / 128.f) - mu * mu + 1e-5f);
#pragma unroll
  for (int n = 0; n < 8; ++n) {
    const f32x4 G = *(const f32x4*)(gvec + n * 16 + q * 4);
    const f32x4 Bv = *(const f32x4*)(bvec + n * 16 + q * 4);
    f32x4 o;
    bf16x4 db;
#pragma unroll
    for (int j = 0; j < 4; ++j) {
      const float d = (acc[n][j] - mu) * rs * G[j] + Bv[j];
      o[j] = R[n][j] + d;
      db[j] = (__bf16)d;
    }
    if (NT)
      __builtin_nontemporal_store(o, (f32x4*)(op + n * 16 + q * 4));
    else
      *(f32x4*)(op + n * 16 + q * 4) = o;
    if (STORE_D) *(bf16x4*)(dp + n * 16 + q * 4) = db;
  }
}

// Edge: out0 = gm + LN(tanh(gm.W1a + P1[src] + P2[dst]))*g+b. 1 tile/wave.
// W fragments straight from global (L1/L2-hot); no LDS, no barrier.
template <bool STORE_D>
__global__ __launch_bounds__(256) void edge_kernel(
    const float* __restrict__ gm, const int* __restrict__ pair,
    const __bf16* __restrict__ P1, const __bf16* __restrict__ P2,
    const __bf16* __restrict__ WF, const float* __restrict__ gvec,
    const float* __restrict__ bvec, float* __restrict__ out,
    __bf16* __restrict__ delta_out) {
  const int tid = threadIdx.x, lane = tid & 63, wid = tid >> 6;
  const int r = lane & 15, q = lane >> 4;
  const __bf16* wl = WF + lane * 8;
  const int row = ((blockIdx.x * 4 + wid) << 4) + r;

  // independent long-latency loads first
  const int2 sd = *(const int2*)(pair + 2 * (size_t)row);
  const float* pa = gm + (size_t)row * 128;
  f32x4 F[4][2];
#pragma unroll
  for (int kk = 0; kk < 4; ++kk) {
    F[kk][0] = *(const f32x4*)(pa + kk * 32 + q * 8);
    F[kk][1] = *(const f32x4*)(pa + kk * 32 + q * 8 + 4);
  }
  // gathers (single dependent hop on sd); consumed only after MFMA
  bf16x4 pg1[8], pg2[8];
  {
    const __bf16* p1 = P1 + (size_t)sd.x * 128 + q * 4;
    const __bf16* p2 = P2 + (size_t)sd.y * 128 + q * 4;
#pragma unroll
    for (int n = 0; n < 8; ++n) {
      pg1[n] = *(const bf16x4*)(p1 + n * 16);
      pg2[n] = *(const bf16x4*)(p2 + n * 16);
    }
  }
  // residual row (independent; same lines as F -> cache-hot)
  f32x4 R[8];
#pragma unroll
  for (int n = 0; n < 8; ++n) R[n] = *(const f32x4*)(pa + n * 16 + q * 4);

  bf16x8 ab[4];
#pragma unroll
  for (int kk = 0; kk < 4; ++kk)
#pragma unroll
    for (int j = 0; j < 4; ++j) {
      ab[kk][j] = (__bf16)F[kk][0][j];
      ab[kk][4 + j] = (__bf16)F[kk][1][j];
    }
  f32x4 acc[8] = {};
#pragma unroll
  for (int kk = 0; kk < 4; ++kk)
#pragma unroll
    for (int n = 0; n < 8; ++n)
      acc[n] = __builtin_amdgcn_mfma_f32_16x16x32_bf16(
          *(const bf16x8*)(wl + (kk * 8 + n) * 512), ab[kk], acc[n], 0, 0, 0);
  // post-MFMA gather add
#pragma unroll
  for (int n = 0; n < 8; ++n)
#pragma unroll
    for (int j = 0; j < 4; ++j)
      acc[n][j] += (float)pg1[n][j] + (float)pg2[n][j];

  mlp_epilogue<STORE_D, true>(acc, R, gvec, bvec, q, out + (size_t)row * 128,
                              STORE_D ? delta_out + (size_t)row * 128 : nullptr);
}

// Fused rect: P1 = bf16(rect.W1b) AND out1 = rect + mlp(rect, W3). 1 tile/wave.
__global__ __launch_bounds__(256) void rect_fused_kernel(
    const float* __restrict__ rect, const __bf16* __restrict__ WFb,
    const __bf16* __restrict__ WF3, const float* __restrict__ gvec,
    const float* __restrict__ bvec, float* __restrict__ out1,
    __bf16* __restrict__ P1) {
  const int tid = threadIdx.x, lane = tid & 63, wid = tid >> 6;
  const int r = lane & 15, q = lane >> 4;
  const __bf16* wlb = WFb + lane * 8;
  const __bf16* wl3 = WF3 + lane * 8;
  const int row = ((blockIdx.x * 4 + wid) << 4) + r;
  const float* pa = rect + (size_t)row * 128;
  f32x4 F[4][2];
#pragma unroll
  for (int kk = 0; kk < 4; ++kk) {
    F[kk][0] = *(const f32x4*)(pa + kk * 32 + q * 8);
    F[kk][1] = *(const f32x4*)(pa + kk * 32 + q * 8 + 4);
  }
  f32x4 R[8];
#pragma unroll
  for (int n = 0; n < 8; ++n) R[n] = *(const f32x4*)(pa + n * 16 + q * 4);
  bf16x8 ab[4];
#pragma unroll
  for (int kk = 0; kk < 4; ++kk)
#pragma unroll
    for (int j = 0; j < 4; ++j) {
      ab[kk][j] = (__bf16)F[kk][0][j];
      ab[kk][4 + j] = (__bf16)F[kk][1][j];
    }
  f32x4 acc[8] = {};
#pragma unroll
  for (int kk = 0; kk < 4; ++kk)
#pragma unroll
    for (int n = 0; n < 8; ++n)
      acc[n] = __builtin_amdgcn_mfma_f32_16x16x32_bf16(
          *(const bf16x8*)(wlb + (kk * 8 + n) * 512), ab[kk], acc[n], 0, 0, 0);
  __bf16* pp = P1 + (size_t)row * 128;
#pragma unroll
  for (int n = 0; n < 8; ++n) {
    bf16x4 o;
#pragma unroll
    for (int j = 0; j < 4; ++j) o[j] = (__bf16)acc[n][j];
    *(bf16x4*)(pp + n * 16 + q * 4) = o;  // cached: re-read by edge_kernel
  }
  f32x4 acc2[8] = {};
#pragma unroll
  for (int kk = 0; kk < 4; ++kk)
#pragma unroll
    for (int n = 0; n < 8; ++n)
      acc2[n] = __builtin_amdgcn_mfma_f32_16x16x32_bf16(
          *(const bf16x8*)(wl3 + (kk * 8 + n) * 512), ab[kk], acc2[n], 0, 0, 0);
  mlp_epilogue<false, true>(acc2, R, gvec, bvec, q, out1 + (size_t)row * 128,
                            nullptr);
}

// Plain K=128 MLP (fallback rect path). 1 tile/wave.
__global__ __launch_bounds__(256) void mlp128_kernel(
    const float* __restrict__ A, const __bf16* __restrict__ WFx,
    const float* __restrict__ gvec, const float* __restrict__ bvec,
    float* __restrict__ out, int M) {
  const int tid = threadIdx.x, lane = tid & 63, wid = tid >> 6;
  const int r = lane & 15, q = lane >> 4;
  const __bf16* wl = WFx + lane * 8;
  const int t = blockIdx.x * 4 + wid;
  if (t >= (M >> 4)) return;
  const int row = (t << 4) + r;
  const float* pa = A + (size_t)row * 128;
  f32x4 F[4][2];
#pragma unroll
  for (int kk = 0; kk < 4; ++kk) {
    F[kk][0] = *(const f32x4*)(pa + kk * 32 + q * 8);
    F[kk][1] = *(const f32x4*)(pa + kk * 32 + q * 8 + 4);
  }
  bf16x8 ab[4];
#pragma unroll
  for (int kk = 0; kk < 4; ++kk)
#pragma unroll
    for (int j = 0; j < 4; ++j) {
      ab[kk][j] = (__bf16)F[kk][0][j];
      ab[kk][4 + j] = (__bf16)F[kk][1][j];
    }
  f32x4 acc[8] = {};
#pragma unroll
  for (int kk = 0; kk < 4; ++kk)
#pragma unroll
    for (int n = 0; n < 8; ++n)
      acc[n] = __builtin_amdgcn_mfma_f32_16x16x32_bf16(
          *(const bf16x8*)(wl + (kk * 8 + n) * 512), ab[kk], acc[n], 0, 0, 0);
  f32x4 R[8];
#pragma unroll
  for (int n = 0; n < 8; ++n) R[n] = *(const f32x4*)(pa + n * 16 + q * 4);
  mlp_epilogue<false, true>(acc, R, gvec, bvec, q, out + (size_t)row * 128,
                            nullptr);
}

// Dense K=128 linear, bf16 out (P2 / P1 fallback). 1 tile/wave.
__global__ __launch_bounds__(256) void lin_kernel(
    const float* __restrict__ A, const __bf16* __restrict__ WFx,
    __bf16* __restrict__ out, int M) {
  const int tid = threadIdx.x, lane = tid & 63, wid = tid >> 6;
  const int r = lane & 15, q = lane >> 4;
  const __bf16* wl = WFx + lane * 8;
  const int t = blockIdx.x * 4 + wid;
  if (t >= (M >> 4)) return;
  const int row = (t << 4) + r;
  const float* pa = A + (size_t)row * 128;
  f32x4 F[4][2];
#pragma unroll
  for (int kk = 0; kk < 4; ++kk) {
    F[kk][0] = *(const f32x4*)(pa + kk * 32 + q * 8);
    F[kk][1] = *(const f32x4*)(pa + kk * 32 + q * 8 + 4);
  }
  bf16x8 ab[4];
#pragma unroll
  for (int kk = 0; kk < 4; ++kk)
#pragma unroll
    for (int j = 0; j < 4; ++j) {
      ab[kk][j] = (__bf16)F[kk][0][j];
      ab[kk][4 + j] = (__bf16)F[kk][1][j];
    }
  f32x4 acc[8] = {};
#pragma unroll
  for (int kk = 0; kk < 4; ++kk)
#pragma unroll
    for (int n = 0; n < 8; ++n)
      acc[n] = __builtin_amdgcn_mfma_f32_16x16x32_bf16(
          *(const bf16x8*)(wl + (kk * 8 + n) * 512), ab[kk], acc[n], 0, 0, 0);
  __bf16* po = out + (size_t)row * 128;
#pragma unroll
  for (int n = 0; n < 8; ++n) {
    bf16x4 o;
#pragma unroll
    for (int j = 0; j < 4; ++j) o[j] = (__bf16)acc[n][j];
    *(bf16x4*)(po + n * 16 + q * 4) = o;
  }
}

// Node MLP: K=256, A = x2 bf16 rows, resid = mesh. 1 tile/wave.
__global__ __launch_bounds__(256) void node_kernel(
    const __bf16* __restrict__ Ab, const __bf16* __restrict__ WF2,
    const float* __restrict__ gvec, const float* __restrict__ bvec,
    const float* __restrict__ resid, float* __restrict__ out, int M) {
  const int tid = threadIdx.x, lane = tid & 63, wid = tid >> 6;
  const int r = lane & 15, q = lane >> 4;
  const __bf16* wl = WF2 + lane * 8;
  const int t = blockIdx.x * 4 + wid;
  if (t >= (M >> 4)) return;
  const int row = (t << 4) + r;
  const __bf16* pb = Ab + (size_t)row * 256 + q * 8;
  bf16x8 ab[8];
#pragma unroll
  for (int kk = 0; kk < 8; ++kk) ab[kk] = *(const bf16x8*)(pb + kk * 32);
  f32x4 R[8];
#pragma unroll
  for (int n = 0; n < 8; ++n)
    R[n] = *(const f32x4*)(resid + (size_t)row * 128 + n * 16 + q * 4);
  f32x4 acc[8] = {};
#pragma unroll
  for (int kk = 0; kk < 8; ++kk)
#pragma unroll
    for (int n = 0; n < 8; ++n)
      acc[n] = __builtin_amdgcn_mfma_f32_16x16x32_bf16(
          *(const bf16x8*)(wl + (kk * 8 + n) * 512), ab[kk], acc[n], 0, 0, 0);
  mlp_epilogue<false, true>(acc, R, gvec, bvec, q, out + (size_t)row * 128,
                            nullptr);
}

// x2[n] = concat(bf16(mesh[n]), bf16(mean_k coef*delta[eid[n][k]]))
template <bool FROM_WS>
__global__ __launch_bounds__(256) void agg_kernel(
    const __bf16* __restrict__ dws, const float* __restrict__ out0,
    const float* __restrict__ gm, const float* __restrict__ mesh,
    const int* __restrict__ eid, const float* __restrict__ coef,
    __bf16* __restrict__ x2) {
  __shared__ int eid_s[512];
  __shared__ float cf_s[512];
  const int t = threadIdx.x;
  const int n0 = blockIdx.x * 16;
  for (int i = t; i < 512; i += 256) {
    eid_s[i] = eid[n0 * 32 + i];
    cf_s[i] = coef[n0 * 32 + i];
  }
  __syncthreads();
  const int rl = t >> 4;
  const int d8 = (t & 15) * 8;
  const int row = n0 + rl;
  float acc[8] = {0, 0, 0, 0, 0, 0, 0, 0};
#pragma unroll 8
  for (int k = 0; k < 32; ++k) {
    const int e = eid_s[rl * 32 + k];
    const float cf = cf_s[rl * 32 + k];
    if (FROM_WS) {
      bf16x8 v = *(const bf16x8*)(dws + (size_t)e * 128 + d8);
#pragma unroll
      for (int j = 0; j < 8; ++j) acc[j] += cf * (float)v[j];
    } else {
      const float* po = out0 + (size_t)e * 128 + d8;
      const float* pg = gm + (size_t)e * 128 + d8;
      f32x4 o0 = *(const f32x4*)po, o1 = *(const f32x4*)(po + 4);
      f32x4 g0 = *(const f32x4*)pg, g1 = *(const f32x4*)(pg + 4);
#pragma unroll
      for (int j = 0; j < 4; ++j) {
        acc[j] += cf * (o0[j] - g0[j]);
        acc[4 + j] += cf * (o1[j] - g1[j]);
      }
    }
  }
  const float* pm = mesh + (size_t)row * 128 + d8;
  f32x4 m0 = *(const f32x4*)pm, m1 = *(const f32x4*)(pm + 4);
  bf16x8 mv, av;
#pragma unroll
  for (int j = 0; j < 4; ++j) {
    mv[j] = (__bf16)m0[j];
    mv[4 + j] = (__bf16)m1[j];
  }
#pragma unroll
  for (int j = 0; j < 8; ++j) av[j] = (__bf16)(acc[j] * (1.0f / 32.0f));
  *(bf16x8*)(x2 + (size_t)row * 256 + d8) = mv;
  *(bf16x8*)(x2 + (size_t)row * 256 + 128 + d8) = av;
}

extern "C" void kernel_launch(void* const* d_in, const int* in_sizes, int n_in,
                              void* d_out, int out_size, void* d_ws,
                              size_t ws_size, hipStream_t stream) {
  const float* gm = (const float*)d_in[0];
  const float* rect = (const float*)d_in[1];
  const float* mesh = (const float*)d_in[2];
  const int* pair = (const int*)d_in[3];
  const int* eid = (const int*)d_in[4];
  const float* coef = (const float*)d_in[5];
  const float* W1 = (const float*)d_in[6];
  const float* g1 = (const float*)d_in[7];
  const float* b1 = (const float*)d_in[8];
  const float* W2 = (const float*)d_in[9];
  const float* g2 = (const float*)d_in[10];
  const float* b2 = (const float*)d_in[11];
  const float* W3 = (const float*)d_in[12];
  const float* g3 = (const float*)d_in[13];
  const float* b3 = (const float*)d_in[14];

  float* out0 = (float*)d_out;
  float* out1 = out0 + (size_t)E_CNT * 128;
  float* out2 = out1 + (size_t)NG_CNT * 128;

  // fragment buffer at the tail of ws (192 KB, 64B-aligned)
  const size_t wfBytes = (size_t)WF_TOT * 2;
  const size_t wfoff = (ws_size - wfBytes) & ~(size_t)63;
  __bf16* WF = (__bf16*)((char*)d_ws + wfoff);

  const size_t deltaE = (size_t)E_CNT * 128;  // bf16 elems
  const size_t x2E = (size_t)NM_CNT * 256;
  const size_t p1E = (size_t)NG_CNT * 128;
  const bool fastD = wfoff >= (deltaE + x2E) * 2;
  const bool fastP = wfoff >= (deltaE + x2E + p1E) * 2;

  __bf16* delta = (__bf16*)d_ws;
  __bf16* x2 = fastD ? delta + deltaE : (__bf16*)d_ws;
  __bf16* P1ws = delta + deltaE + x2E;
  __bf16* P2 = (__bf16*)out2;  // overwritten by node_kernel at the end

  convert_w_kernel<<<48, 256, 0, stream>>>(W1, W2, W3, WF);

  const __bf16* P1;
  if (fastP) {
    rect_fused_kernel<<<1024, 256, 0, stream>>>(rect, WF + WF_B, WF + WF_3, g3,
                                                b3, out1, P1ws);
    P1 = P1ws;
  } else {
    lin_kernel<<<1024, 256, 0, stream>>>(rect, WF + WF_B, (__bf16*)out1,
                                         NG_CNT);
    P1 = (const __bf16*)out1;
  }
  lin_kernel<<<128, 256, 0, stream>>>(mesh, WF + WF_C, P2, NM_CNT);

  if (fastD) {
    edge_kernel<true><<<4096, 256, 0, stream>>>(gm, pair, P1, P2, WF + WF_A,
                                                g1, b1, out0, delta);
    agg_kernel<true><<<512, 256, 0, stream>>>(delta, nullptr, nullptr, mesh,
                                              eid, coef, x2);
  } else {
    edge_kernel<false><<<4096, 256, 0, stream>>>(gm, pair, P1, P2, WF + WF_A,
                                                 g1, b1, out0, nullptr);
    agg_kernel<false><<<512, 256, 0, stream>>>(nullptr, out0, gm, mesh, eid,
                                               coef, x2);
  }
  if (!fastP) {  // rect MLP overwrites out1 only after edge consumed P1
    mlp128_kernel<<<1024, 256, 0, stream>>>(rect, WF + WF_3, g3, b3, out1,
                                            NG_CNT);
  }
  node_kernel<<<128, 256, 0, stream>>>(x2, WF + WF_2, g2, b2, mesh, out2,
                                       NM_CNT);
}